// Round 1
// baseline (379.122 us; speedup 1.0000x reference)
//
#include <hip/hip_runtime.h>

constexpr int B = 16, N = 128, D = 128, DN0 = 64, DE0 = 16;

// ---------------------------------------------------------------------------
// K1: xi0 = x @ Wi0 + b_msg0 ; xj0 = x @ Wj0      (rows = b*N+i, 2048 blocks)
// ---------------------------------------------------------------------------
__global__ __launch_bounds__(128) void k_pre0(
    const float* __restrict__ x, const float* __restrict__ wm0,
    const float* __restrict__ bm0,
    float* __restrict__ xi0, float* __restrict__ xj0) {
  const int row = blockIdx.x;
  const int c = threadIdx.x;
  __shared__ float xr[DN0];
  if (c < DN0) xr[c] = x[row * DN0 + c];
  __syncthreads();
  float ai = bm0[c], aj = 0.f;
  #pragma unroll 8
  for (int k = 0; k < DN0; ++k) {
    const float xv = xr[k];
    ai = fmaf(xv, wm0[k * D + c], ai);
    aj = fmaf(xv, wm0[(DN0 + k) * D + c], aj);
  }
  xi0[row * D + c] = ai;
  xj0[row * D + c] = aj;
}

// ---------------------------------------------------------------------------
// K2: layer-0 edge kernel. Per (b,i) row: T0 = e_row[128x16] @ We0[16x128],
// msg0 = relu(xi0_i + xj0_j + T0)*A, agg0 = sum_j msg0. One block per row.
// Thread t: cb = t&15, jb = t>>4; handles j = jb+16p, c = cb+16q (8x8 tile).
// ---------------------------------------------------------------------------
__global__ __launch_bounds__(256) void k_edge0(
    const int* __restrict__ ei, const float* __restrict__ eattr,
    const float* __restrict__ wm0,
    const float* __restrict__ xi0, const float* __restrict__ xj0,
    float* __restrict__ msg0, float* __restrict__ agg0) {
  const int row = blockIdx.x;
  const int b = row >> 7;
  const int t = threadIdx.x;
  const int cb = t & 15, jb = t >> 4;

  __shared__ float e_row[N][20];        // pad 20: 16B-aligned f4 stores, cf reads
  __shared__ float w_t[DE0][D];
  __shared__ float amask[N];
  __shared__ float xi_r[D];
  __shared__ float hpart[16][16][8];

  // stage e_attr row (2048 floats) and We0 (2048 floats)
  const float4* esrc = (const float4*)(eattr + (size_t)row * N * DE0);
  const float4* wsrc = (const float4*)(wm0 + 2 * DN0 * D);
  #pragma unroll
  for (int u = 0; u < 2; ++u) {
    const int idx4 = u * 256 + t;       // 0..511
    const int j = idx4 >> 2;            // 4 float4 per 16-float row
    const int k4 = (idx4 & 3) * 4;
    *(float4*)&e_row[j][k4] = esrc[idx4];
    ((float4*)&w_t[0][0])[idx4] = wsrc[idx4];
  }
  if (t < N) {
    amask[t] = (float)ei[(size_t)row * N + t];
    xi_r[t] = xi0[row * D + t];
  }
  __syncthreads();

  float acc[8][8] = {};
  #pragma unroll 4
  for (int k = 0; k < DE0; ++k) {
    float av[8], wv[8];
    #pragma unroll
    for (int p = 0; p < 8; ++p) av[p] = e_row[jb + 16 * p][k];
    #pragma unroll
    for (int q = 0; q < 8; ++q) wv[q] = w_t[k][cb + 16 * q];
    #pragma unroll
    for (int p = 0; p < 8; ++p)
      #pragma unroll
      for (int q = 0; q < 8; ++q)
        acc[p][q] = fmaf(av[p], wv[q], acc[p][q]);
  }

  // epilogue: relu+mask, write msg0, partial agg
  float hq[8] = {};
  const float* xjb = xj0 + (size_t)b * N * D;
  float* mrow = msg0 + (size_t)row * N * D;
  #pragma unroll
  for (int p = 0; p < 8; ++p) {
    const int j = jb + 16 * p;
    const float am = amask[j];
    #pragma unroll
    for (int q = 0; q < 8; ++q) {
      const int c = cb + 16 * q;
      float v = xi_r[c] + xjb[j * D + c] + acc[p][q];
      v = fmaxf(v, 0.f) * am;
      mrow[j * D + c] = v;
      hq[q] += v;
    }
  }
  #pragma unroll
  for (int q = 0; q < 8; ++q) hpart[jb][cb][q] = hq[q];
  __syncthreads();
  if (t < D) {
    const int c = t;
    float s = 0.f;
    #pragma unroll
    for (int g = 0; g < 16; ++g) s += hpart[g][c & 15][c >> 4];
    agg0[row * D + c] = s;
  }
}

// ---------------------------------------------------------------------------
// K3 / K5: node update + next layer's xi/xj precompute. One block per row.
// out_x may be null (layer-1 variant stores x2=0.5*(x1+x1_new) only to regs).
// ---------------------------------------------------------------------------
__global__ __launch_bounds__(128) void k_node0(
    const float* __restrict__ x0, const float* __restrict__ agg0,
    const float* __restrict__ wn0, const float* __restrict__ bn0,
    const float* __restrict__ wm1, const float* __restrict__ bm1,
    float* __restrict__ x1, float* __restrict__ xi1, float* __restrict__ xj1) {
  const int row = blockIdx.x;
  const int c = threadIdx.x;
  __shared__ float xr[DN0], ar[D], x1r[D];
  if (c < DN0) xr[c] = x0[row * DN0 + c];
  ar[c] = agg0[row * D + c];
  __syncthreads();
  float a = bn0[c];
  #pragma unroll 8
  for (int k = 0; k < DN0; ++k) a = fmaf(xr[k], wn0[k * D + c], a);
  #pragma unroll 8
  for (int k = 0; k < D; ++k) a = fmaf(ar[k], wn0[(DN0 + k) * D + c], a);
  a = fmaxf(a, 0.f);
  x1[row * D + c] = a;
  x1r[c] = a;
  __syncthreads();
  float ai = bm1[c], aj = 0.f;
  #pragma unroll 8
  for (int k = 0; k < D; ++k) {
    const float xv = x1r[k];
    ai = fmaf(xv, wm1[k * D + c], ai);
    aj = fmaf(xv, wm1[(D + k) * D + c], aj);
  }
  xi1[row * D + c] = ai;
  xj1[row * D + c] = aj;
}

__global__ __launch_bounds__(128) void k_node1(
    const float* __restrict__ x1, const float* __restrict__ agg1,
    const float* __restrict__ wn1, const float* __restrict__ bn1,
    const float* __restrict__ wm2, const float* __restrict__ bm2,
    float* __restrict__ xi2, float* __restrict__ xj2) {
  const int row = blockIdx.x;
  const int c = threadIdx.x;
  __shared__ float x1r[D], ar[D], x2r[D];
  x1r[c] = x1[row * D + c];
  ar[c] = agg1[row * D + c];
  __syncthreads();
  float a = bn1[c];
  #pragma unroll 8
  for (int k = 0; k < D; ++k) a = fmaf(x1r[k], wn1[k * D + c], a);
  #pragma unroll 8
  for (int k = 0; k < D; ++k) a = fmaf(ar[k], wn1[(D + k) * D + c], a);
  x2r[c] = 0.5f * (x1r[c] + fmaxf(a, 0.f));
  __syncthreads();
  float ai = bm2[c], aj = 0.f;
  #pragma unroll 8
  for (int k = 0; k < D; ++k) {
    const float xv = x2r[k];
    ai = fmaf(xv, wm2[k * D + c], ai);
    aj = fmaf(xv, wm2[(D + k) * D + c], aj);
  }
  xi2[row * D + c] = ai;
  xj2[row * D + c] = aj;
}

// ---------------------------------------------------------------------------
// K4/K6: layer-1/2 edge kernel. Per (b,i): T = em_row[128x128] @ We[128x128]
// (k-tiled by 32), msg = relu(xi_i + xj_j + T)*A.
// MODE 0 (layer 1): e_mid = 0.5*(msg0+msg1) written IN PLACE over msg0;
//                   aggout = agg1 = sum_j msg1.
// MODE 1 (layer 2): nothing written to em; aggout = rowsum = sum_j msg2
//                   (later reduced over i by k_head).
// ---------------------------------------------------------------------------
template <int MODE>
__global__ __launch_bounds__(256) void k_edgeN(
    const int* __restrict__ ei, const float* __restrict__ We,
    const float* __restrict__ xi, const float* __restrict__ xj,
    float* __restrict__ em, float* __restrict__ aggout) {
  const int row = blockIdx.x;
  const int b = row >> 7;
  const int t = threadIdx.x;
  const int cb = t & 15, jb = t >> 4;

  __shared__ float a_t[N][36];          // pad 36: 16B-aligned, conflict-free
  __shared__ float w_t[32][D];
  __shared__ float amask[N];
  __shared__ float xi_r[D];
  __shared__ float hpart[16][16][8];

  if (t < N) {
    amask[t] = (float)ei[(size_t)row * N + t];
    xi_r[t] = xi[row * D + t];
  }

  float acc[8][8] = {};
  const float* arow = em + (size_t)row * N * D;

  for (int kt = 0; kt < 4; ++kt) {
    // stage a-tile (128x32) and w-tile (32x128), 1024 float4 each
    #pragma unroll
    for (int u = 0; u < 4; ++u) {
      const int idx4 = u * 256 + t;     // 0..1023
      const int j = idx4 >> 3;          // 8 float4 per 32-float slice
      const int k4 = (idx4 & 7) * 4;
      *(float4*)&a_t[j][k4] = *(const float4*)&arow[j * D + kt * 32 + k4];
      ((float4*)&w_t[0][0])[idx4] = ((const float4*)(We + kt * 32 * D))[idx4];
    }
    __syncthreads();
    #pragma unroll 4
    for (int k = 0; k < 32; ++k) {
      float av[8], wv[8];
      #pragma unroll
      for (int p = 0; p < 8; ++p) av[p] = a_t[jb + 16 * p][k];
      #pragma unroll
      for (int q = 0; q < 8; ++q) wv[q] = w_t[k][cb + 16 * q];
      #pragma unroll
      for (int p = 0; p < 8; ++p)
        #pragma unroll
        for (int q = 0; q < 8; ++q)
          acc[p][q] = fmaf(av[p], wv[q], acc[p][q]);
    }
    __syncthreads();
  }

  float hq[8] = {};
  const float* xjb = xj + (size_t)b * N * D;
  float* mrow = em + (size_t)row * N * D;
  #pragma unroll
  for (int p = 0; p < 8; ++p) {
    const int j = jb + 16 * p;
    const float am = amask[j];
    #pragma unroll
    for (int q = 0; q < 8; ++q) {
      const int c = cb + 16 * q;
      float m1 = fmaxf(xi_r[c] + xjb[j * D + c] + acc[p][q], 0.f) * am;
      if (MODE == 0) {
        const float m0 = mrow[j * D + c];       // re-read msg0 (L2-hot)
        mrow[j * D + c] = 0.5f * (m0 + m1);     // e_mid in place
      }
      hq[q] += m1;
    }
  }
  #pragma unroll
  for (int q = 0; q < 8; ++q) hpart[jb][cb][q] = hq[q];
  __syncthreads();
  if (t < D) {
    const int c = t;
    float s = 0.f;
    #pragma unroll
    for (int g = 0; g < 16; ++g) s += hpart[g][c & 15][c >> 4];
    aggout[row * D + c] = s;
  }
}

// ---------------------------------------------------------------------------
// K7: head. h[b] = mean(msg2) via rowsum; 3-layer MLP to scalar. 16 blocks.
// ---------------------------------------------------------------------------
__global__ __launch_bounds__(128) void k_head(
    const float* __restrict__ rowsum,
    const float* __restrict__ w1, const float* __restrict__ b1,
    const float* __restrict__ w2, const float* __restrict__ b2,
    const float* __restrict__ w3, const float* __restrict__ b3,
    float* __restrict__ out) {
  const int b = blockIdx.x;
  const int c = threadIdx.x;
  __shared__ float hr[D], h1r[D], h2r[D];
  const float* rs = rowsum + (size_t)b * N * D;
  float s = 0.f;
  for (int i = 0; i < N; ++i) s += rs[i * D + c];
  hr[c] = s * (1.f / (N * N));
  __syncthreads();
  float a = b1[c];
  #pragma unroll 8
  for (int k = 0; k < D; ++k) a = fmaf(hr[k], w1[k * D + c], a);
  h1r[c] = fmaxf(a, 0.f);
  __syncthreads();
  a = b2[c];
  #pragma unroll 8
  for (int k = 0; k < D; ++k) a = fmaf(h1r[k], w2[k * D + c], a);
  h2r[c] = fmaxf(a, 0.f);
  __syncthreads();
  hr[c] = h2r[c] * w3[c];
  __syncthreads();
  if (c == 0) {
    float s2 = b3[0];
    for (int k = 0; k < D; ++k) s2 += hr[k];
    out[b] = s2;
  }
}

// ---------------------------------------------------------------------------
extern "C" void kernel_launch(void* const* d_in, const int* in_sizes, int n_in,
                              void* d_out, int out_size, void* d_ws, size_t ws_size,
                              hipStream_t stream) {
  const int*   ei  = (const int*)d_in[0];
  const float* x0  = (const float*)d_in[1];
  const float* ea  = (const float*)d_in[2];
  const float* wm0 = (const float*)d_in[3];
  const float* bm0 = (const float*)d_in[4];
  const float* wn0 = (const float*)d_in[5];
  const float* bn0 = (const float*)d_in[6];
  const float* wm1 = (const float*)d_in[7];
  const float* bm1 = (const float*)d_in[8];
  const float* wn1 = (const float*)d_in[9];
  const float* bn1 = (const float*)d_in[10];
  const float* wm2 = (const float*)d_in[11];
  const float* bm2 = (const float*)d_in[12];
  const float* wh1 = (const float*)d_in[15];
  const float* bh1 = (const float*)d_in[16];
  const float* wh2 = (const float*)d_in[17];
  const float* bh2 = (const float*)d_in[18];
  const float* wh3 = (const float*)d_in[19];
  const float* bh3 = (const float*)d_in[20];
  float* out = (float*)d_out;

  float* ws = (float*)d_ws;
  size_t off = 0;
  float* msg0 = ws + off; off += (size_t)B * N * N * D;   // 33.5M f, e_mid in place
  float* xi0  = ws + off; off += (size_t)B * N * D;
  float* xj0  = ws + off; off += (size_t)B * N * D;
  float* agg0 = ws + off; off += (size_t)B * N * D;
  float* x1   = ws + off; off += (size_t)B * N * D;
  float* xi1  = ws + off; off += (size_t)B * N * D;
  float* xj1  = ws + off; off += (size_t)B * N * D;
  float* agg1 = ws + off; off += (size_t)B * N * D;
  float* xi2  = ws + off; off += (size_t)B * N * D;
  float* xj2  = ws + off; off += (size_t)B * N * D;
  float* rsum = ws + off; off += (size_t)B * N * D;

  const int rows = B * N;   // 2048
  k_pre0 <<<rows, 128, 0, stream>>>(x0, wm0, bm0, xi0, xj0);
  k_edge0<<<rows, 256, 0, stream>>>(ei, ea, wm0, xi0, xj0, msg0, agg0);
  k_node0<<<rows, 128, 0, stream>>>(x0, agg0, wn0, bn0, wm1, bm1, x1, xi1, xj1);
  k_edgeN<0><<<rows, 256, 0, stream>>>(ei, wm1 + 2 * D * D, xi1, xj1, msg0, agg1);
  k_node1<<<rows, 128, 0, stream>>>(x1, agg1, wn1, bn1, wm2, bm2, xi2, xj2);
  k_edgeN<1><<<rows, 256, 0, stream>>>(ei, wm2 + 2 * D * D, xi2, xj2, msg0, rsum);
  k_head <<<B,    128, 0, stream>>>(rsum, wh1, bh1, wh2, bh2, wh3, bh3, out);
}

// Round 2
// 286.032 us; speedup vs baseline: 1.3255x; 1.3255x over previous
//
#include <hip/hip_runtime.h>

constexpr int B = 16, N = 128, D = 128, DN0 = 64, DE0 = 16;
constexpr int PAD = 136;   // fp16 elems per LDS row (128 + 8): 4-bank stagger, conflict-free

typedef _Float16 half8 __attribute__((ext_vector_type(8)));
typedef _Float16 half4 __attribute__((ext_vector_type(4)));
typedef float floatx4 __attribute__((ext_vector_type(4)));

// ---------------------------------------------------------------------------
// K0: WeT prep. WeT_l[c][k] = (fp16) w_msg_l[2D+k][c], layers 1 and 2.
// ---------------------------------------------------------------------------
__global__ __launch_bounds__(128) void k_wprep(
    const float* __restrict__ wm1, const float* __restrict__ wm2,
    _Float16* __restrict__ weT1, _Float16* __restrict__ weT2) {
  const int bid = blockIdx.x;            // 256 blocks
  const int layer = bid >> 7, c = bid & 127;
  const int k = threadIdx.x;
  const float* src = layer ? wm2 : wm1;
  _Float16* dst = layer ? weT2 : weT1;
  dst[c * D + k] = (_Float16)src[(2 * D + k) * D + c];
}

// ---------------------------------------------------------------------------
// K1: xi0 = x @ Wi0 + b_msg0 ; xj0 = x @ Wj0      (2048 blocks)
// ---------------------------------------------------------------------------
__global__ __launch_bounds__(128) void k_pre0(
    const float* __restrict__ x, const float* __restrict__ wm0,
    const float* __restrict__ bm0,
    float* __restrict__ xi0, float* __restrict__ xj0) {
  const int row = blockIdx.x;
  const int c = threadIdx.x;
  __shared__ float xr[DN0];
  if (c < DN0) xr[c] = x[row * DN0 + c];
  __syncthreads();
  float ai = bm0[c], aj = 0.f;
  #pragma unroll 8
  for (int k = 0; k < DN0; ++k) {
    const float xv = xr[k];
    ai = fmaf(xv, wm0[k * D + c], ai);
    aj = fmaf(xv, wm0[(DN0 + k) * D + c], aj);
  }
  xi0[row * D + c] = ai;
  xj0[row * D + c] = aj;
}

// ---------------------------------------------------------------------------
// K2: layer-0 edge kernel (K=16 matmul, VALU fp32). msg0 stored as fp16.
// ---------------------------------------------------------------------------
__global__ __launch_bounds__(256) void k_edge0(
    const int* __restrict__ ei, const float* __restrict__ eattr,
    const float* __restrict__ wm0,
    const float* __restrict__ xi0, const float* __restrict__ xj0,
    _Float16* __restrict__ msg0, float* __restrict__ agg0) {
  const int row = blockIdx.x;
  const int b = row >> 7;
  const int t = threadIdx.x;
  const int cb = t & 15, jb = t >> 4;

  __shared__ float e_row[N][20];
  __shared__ float w_t[DE0][D];
  __shared__ float amask[N];
  __shared__ float xi_r[D];
  __shared__ float hpart[16][16][8];

  const float4* esrc = (const float4*)(eattr + (size_t)row * N * DE0);
  const float4* wsrc = (const float4*)(wm0 + 2 * DN0 * D);
  #pragma unroll
  for (int u = 0; u < 2; ++u) {
    const int idx4 = u * 256 + t;
    const int j = idx4 >> 2;
    const int k4 = (idx4 & 3) * 4;
    *(float4*)&e_row[j][k4] = esrc[idx4];
    ((float4*)&w_t[0][0])[idx4] = wsrc[idx4];
  }
  if (t < N) {
    amask[t] = (float)ei[(size_t)row * N + t];
    xi_r[t] = xi0[row * D + t];
  }
  __syncthreads();

  float acc[8][8] = {};
  #pragma unroll 4
  for (int k = 0; k < DE0; ++k) {
    float av[8], wv[8];
    #pragma unroll
    for (int p = 0; p < 8; ++p) av[p] = e_row[jb + 16 * p][k];
    #pragma unroll
    for (int q = 0; q < 8; ++q) wv[q] = w_t[k][cb + 16 * q];
    #pragma unroll
    for (int p = 0; p < 8; ++p)
      #pragma unroll
      for (int q = 0; q < 8; ++q)
        acc[p][q] = fmaf(av[p], wv[q], acc[p][q]);
  }

  float hq[8] = {};
  const float* xjb = xj0 + (size_t)b * N * D;
  _Float16* mrow = msg0 + (size_t)row * N * D;
  #pragma unroll
  for (int p = 0; p < 8; ++p) {
    const int j = jb + 16 * p;
    const float am = amask[j];
    #pragma unroll
    for (int q = 0; q < 8; ++q) {
      const int c = cb + 16 * q;
      float v = xi_r[c] + xjb[j * D + c] + acc[p][q];
      v = fmaxf(v, 0.f) * am;
      mrow[j * D + c] = (_Float16)v;
      hq[q] += v;
    }
  }
  #pragma unroll
  for (int q = 0; q < 8; ++q) hpart[jb][cb][q] = hq[q];
  __syncthreads();
  if (t < D) {
    const int c = t;
    float s = 0.f;
    #pragma unroll
    for (int g = 0; g < 16; ++g) s += hpart[g][c & 15][c >> 4];
    agg0[row * D + c] = s;
  }
}

// ---------------------------------------------------------------------------
// K3 / K5: node update + next layer's xi/xj precompute.
// ---------------------------------------------------------------------------
__global__ __launch_bounds__(128) void k_node0(
    const float* __restrict__ x0, const float* __restrict__ agg0,
    const float* __restrict__ wn0, const float* __restrict__ bn0,
    const float* __restrict__ wm1, const float* __restrict__ bm1,
    float* __restrict__ x1, float* __restrict__ xi1, float* __restrict__ xj1) {
  const int row = blockIdx.x;
  const int c = threadIdx.x;
  __shared__ float xr[DN0], ar[D], x1r[D];
  if (c < DN0) xr[c] = x0[row * DN0 + c];
  ar[c] = agg0[row * D + c];
  __syncthreads();
  float a = bn0[c];
  #pragma unroll 8
  for (int k = 0; k < DN0; ++k) a = fmaf(xr[k], wn0[k * D + c], a);
  #pragma unroll 8
  for (int k = 0; k < D; ++k) a = fmaf(ar[k], wn0[(DN0 + k) * D + c], a);
  a = fmaxf(a, 0.f);
  x1[row * D + c] = a;
  x1r[c] = a;
  __syncthreads();
  float ai = bm1[c], aj = 0.f;
  #pragma unroll 8
  for (int k = 0; k < D; ++k) {
    const float xv = x1r[k];
    ai = fmaf(xv, wm1[k * D + c], ai);
    aj = fmaf(xv, wm1[(D + k) * D + c], aj);
  }
  xi1[row * D + c] = ai;
  xj1[row * D + c] = aj;
}

__global__ __launch_bounds__(128) void k_node1(
    const float* __restrict__ x1, const float* __restrict__ agg1,
    const float* __restrict__ wn1, const float* __restrict__ bn1,
    const float* __restrict__ wm2, const float* __restrict__ bm2,
    float* __restrict__ xi2, float* __restrict__ xj2) {
  const int row = blockIdx.x;
  const int c = threadIdx.x;
  __shared__ float x1r[D], ar[D], x2r[D];
  x1r[c] = x1[row * D + c];
  ar[c] = agg1[row * D + c];
  __syncthreads();
  float a = bn1[c];
  #pragma unroll 8
  for (int k = 0; k < D; ++k) a = fmaf(x1r[k], wn1[k * D + c], a);
  #pragma unroll 8
  for (int k = 0; k < D; ++k) a = fmaf(ar[k], wn1[(D + k) * D + c], a);
  x2r[c] = 0.5f * (x1r[c] + fmaxf(a, 0.f));
  __syncthreads();
  float ai = bm2[c], aj = 0.f;
  #pragma unroll 8
  for (int k = 0; k < D; ++k) {
    const float xv = x2r[k];
    ai = fmaf(xv, wm2[k * D + c], ai);
    aj = fmaf(xv, wm2[(D + k) * D + c], aj);
  }
  xi2[row * D + c] = ai;
  xj2[row * D + c] = aj;
}

// ---------------------------------------------------------------------------
// K4/K6: MFMA edge kernel for layers 1/2. One block per (b,i) row.
// D[c][j] = sum_k WeT[c][k] * em[j][k]  via mfma_f32_16x16x32_f16
//   A-op = WeT (regs, preloaded), B-op = em row tile (LDS, padded 136).
// Wave w owns j in [32w, 32w+32): touches only its own LDS rows.
// MODE 0: e_mid = 0.5*(m0+m1) RMW'd in LDS, coalesced copy-out; agg1 out.
// MODE 1: rowsum out only.
// ---------------------------------------------------------------------------
template <int MODE>
__global__ __launch_bounds__(256, 2) void k_edgeN(
    const int* __restrict__ ei, const _Float16* __restrict__ weT,
    const float* __restrict__ xi, const float* __restrict__ xj,
    _Float16* __restrict__ em, float* __restrict__ aggout) {
  const int row = blockIdx.x;
  const int b = row >> 7;
  const int t = threadIdx.x;
  const int w = t >> 6;
  const int lane = t & 63;
  const int lm = lane & 15;        // MFMA n-dim (j) / A row (c) residue
  const int lq = lane >> 4;        // quad

  __shared__ _Float16 sE[N * PAD];     // em row tile [j][k], 34816 B
  __shared__ float sXi[D];
  __shared__ float sMask[N];
  __shared__ float sHp[4][D];

  // --- preload A fragments (WeT) into registers: 8 ct x 4 ks, L2-hot ---
  half8 aF[8][4];
  #pragma unroll
  for (int ct = 0; ct < 8; ++ct)
    #pragma unroll
    for (int ks = 0; ks < 4; ++ks)
      aF[ct][ks] = *(const half8*)(weT + (16 * ct + lm) * D + 8 * lq + 32 * ks);

  // --- stage em row (32 KB fp16) into padded LDS ---
  const uint4* esrc = (const uint4*)(em + (size_t)row * N * D);
  #pragma unroll
  for (int u = 0; u < 8; ++u) {
    const int idx4 = u * 256 + t;        // 0..2047
    const int j = idx4 >> 4;             // 16 uint4 per 128-fp16 row
    const int k16 = (idx4 & 15) * 8;
    *(uint4*)&sE[j * PAD + k16] = esrc[idx4];
  }
  if (t < N) {
    sMask[t] = (float)ei[(size_t)row * N + t];
    sXi[t] = xi[row * D + t];
  }
  __syncthreads();

  // --- K-loop: 4 ksteps x 16 MFMA; B-frags from own rows only ---
  floatx4 acc[8][2];
  #pragma unroll
  for (int ct = 0; ct < 8; ++ct)
    #pragma unroll
    for (int jt = 0; jt < 2; ++jt)
      acc[ct][jt] = (floatx4){0.f, 0.f, 0.f, 0.f};

  #pragma unroll
  for (int ks = 0; ks < 4; ++ks) {
    const half8 bv0 = *(const half8*)&sE[(32 * w + lm) * PAD + 8 * lq + 32 * ks];
    const half8 bv1 = *(const half8*)&sE[(32 * w + 16 + lm) * PAD + 8 * lq + 32 * ks];
    #pragma unroll
    for (int ct = 0; ct < 8; ++ct) {
      acc[ct][0] = __builtin_amdgcn_mfma_f32_16x16x32_f16(aF[ct][ks], bv0, acc[ct][0], 0, 0, 0);
      acc[ct][1] = __builtin_amdgcn_mfma_f32_16x16x32_f16(aF[ct][ks], bv1, acc[ct][1], 0, 0, 0);
    }
  }

  // --- epilogue: lane element (jt,ct,r): j = 32w+16jt+lm, c = 16ct+4lq+r ---
  floatx4 xiv[8];
  #pragma unroll
  for (int ct = 0; ct < 8; ++ct) xiv[ct] = *(const floatx4*)&sXi[16 * ct + 4 * lq];

  const float* xjb = xj + (size_t)b * N * D;
  floatx4 hacc[8];
  #pragma unroll
  for (int ct = 0; ct < 8; ++ct) hacc[ct] = (floatx4){0.f, 0.f, 0.f, 0.f};

  #pragma unroll
  for (int jt = 0; jt < 2; ++jt) {
    const int j = 32 * w + 16 * jt + lm;
    const float am = sMask[j];
    #pragma unroll
    for (int ct = 0; ct < 8; ++ct) {
      const floatx4 xjv = *(const floatx4*)&xjb[j * D + 16 * ct + 4 * lq];
      floatx4 m1;
      #pragma unroll
      for (int r = 0; r < 4; ++r) {
        float v = xiv[ct][r] + xjv[r] + acc[ct][jt][r];
        m1[r] = fmaxf(v, 0.f) * am;
      }
      hacc[ct] += m1;
      if constexpr (MODE == 0) {
        const int la = j * PAD + 16 * ct + 4 * lq;
        const half4 m0 = *(const half4*)&sE[la];
        half4 mid;
        #pragma unroll
        for (int r = 0; r < 4; ++r) mid[r] = (_Float16)(0.5f * ((float)m0[r] + m1[r]));
        *(half4*)&sE[la] = mid;      // own row: no cross-wave hazard
      }
    }
  }

  // --- agg: wave-local shuffle reduce over lm (j-residues), then cross-wave ---
  #pragma unroll
  for (int m = 1; m < 16; m <<= 1)
    #pragma unroll
    for (int ct = 0; ct < 8; ++ct)
      #pragma unroll
      for (int r = 0; r < 4; ++r)
        hacc[ct][r] += __shfl_xor(hacc[ct][r], m, 64);
  if (lm == 0) {
    #pragma unroll
    for (int ct = 0; ct < 8; ++ct)
      *(floatx4*)&sHp[w][16 * ct + 4 * lq] = hacc[ct];
  }
  __syncthreads();
  if (t < D)
    aggout[row * D + t] = sHp[0][t] + sHp[1][t] + sHp[2][t] + sHp[3][t];

  if constexpr (MODE == 0) {
    // coalesced e_mid copy-out
    uint4* dst = (uint4*)(em + (size_t)row * N * D);
    #pragma unroll
    for (int u = 0; u < 8; ++u) {
      const int idx4 = u * 256 + t;
      const int j = idx4 >> 4;
      const int k16 = (idx4 & 15) * 8;
      dst[idx4] = *(const uint4*)&sE[j * PAD + k16];
    }
  }
}

// ---------------------------------------------------------------------------
// K7: head MLP. 16 blocks.
// ---------------------------------------------------------------------------
__global__ __launch_bounds__(128) void k_head(
    const float* __restrict__ rowsum,
    const float* __restrict__ w1, const float* __restrict__ b1,
    const float* __restrict__ w2, const float* __restrict__ b2,
    const float* __restrict__ w3, const float* __restrict__ b3,
    float* __restrict__ out) {
  const int b = blockIdx.x;
  const int c = threadIdx.x;
  __shared__ float hr[D], h1r[D], h2r[D];
  const float* rs = rowsum + (size_t)b * N * D;
  float s = 0.f;
  for (int i = 0; i < N; ++i) s += rs[i * D + c];
  hr[c] = s * (1.f / (N * N));
  __syncthreads();
  float a = b1[c];
  #pragma unroll 8
  for (int k = 0; k < D; ++k) a = fmaf(hr[k], w1[k * D + c], a);
  h1r[c] = fmaxf(a, 0.f);
  __syncthreads();
  a = b2[c];
  #pragma unroll 8
  for (int k = 0; k < D; ++k) a = fmaf(h1r[k], w2[k * D + c], a);
  h2r[c] = fmaxf(a, 0.f);
  __syncthreads();
  hr[c] = h2r[c] * w3[c];
  __syncthreads();
  if (c == 0) {
    float s2 = b3[0];
    for (int k = 0; k < D; ++k) s2 += hr[k];
    out[b] = s2;
  }
}

// ---------------------------------------------------------------------------
extern "C" void kernel_launch(void* const* d_in, const int* in_sizes, int n_in,
                              void* d_out, int out_size, void* d_ws, size_t ws_size,
                              hipStream_t stream) {
  const int*   ei  = (const int*)d_in[0];
  const float* x0  = (const float*)d_in[1];
  const float* ea  = (const float*)d_in[2];
  const float* wm0 = (const float*)d_in[3];
  const float* bm0 = (const float*)d_in[4];
  const float* wn0 = (const float*)d_in[5];
  const float* bn0 = (const float*)d_in[6];
  const float* wm1 = (const float*)d_in[7];
  const float* bm1 = (const float*)d_in[8];
  const float* wn1 = (const float*)d_in[9];
  const float* bn1 = (const float*)d_in[10];
  const float* wm2 = (const float*)d_in[11];
  const float* bm2 = (const float*)d_in[12];
  const float* wh1 = (const float*)d_in[15];
  const float* bh1 = (const float*)d_in[16];
  const float* wh2 = (const float*)d_in[17];
  const float* bh2 = (const float*)d_in[18];
  const float* wh3 = (const float*)d_in[19];
  const float* bh3 = (const float*)d_in[20];
  float* out = (float*)d_out;

  // workspace: fp16 region first (16B-aligned base), then fp32 arrays
  _Float16* msg0h = (_Float16*)d_ws;                       // [B,N,N,D] fp16, e_mid in place
  _Float16* weT1  = msg0h + (size_t)B * N * N * D;
  _Float16* weT2  = weT1 + D * D;
  float* f = (float*)(weT2 + D * D);
  size_t off = 0;
  const size_t R = (size_t)B * N * D;
  float* xi0  = f + off; off += R;
  float* xj0  = f + off; off += R;
  float* agg0 = f + off; off += R;
  float* x1   = f + off; off += R;
  float* xi1  = f + off; off += R;
  float* xj1  = f + off; off += R;
  float* agg1 = f + off; off += R;
  float* xi2  = f + off; off += R;
  float* xj2  = f + off; off += R;
  float* rsum = f + off; off += R;

  const int rows = B * N;   // 2048
  k_wprep<<<256, 128, 0, stream>>>(wm1, wm2, weT1, weT2);
  k_pre0 <<<rows, 128, 0, stream>>>(x0, wm0, bm0, xi0, xj0);
  k_edge0<<<rows, 256, 0, stream>>>(ei, ea, wm0, xi0, xj0, msg0h, agg0);
  k_node0<<<rows, 128, 0, stream>>>(x0, agg0, wn0, bn0, wm1, bm1, x1, xi1, xj1);
  k_edgeN<0><<<rows, 256, 0, stream>>>(ei, weT1, xi1, xj1, msg0h, agg1);
  k_node1<<<rows, 128, 0, stream>>>(x1, agg1, wn1, bn1, wm2, bm2, xi2, xj2);
  k_edgeN<1><<<rows, 256, 0, stream>>>(ei, weT2, xi2, xj2, msg0h, rsum);
  k_head <<<B,    128, 0, stream>>>(rsum, wh1, bh1, wh2, bh2, wh3, bh3, out);
}